// Round 10
// baseline (377.150 us; speedup 1.0000x reference)
//
#include <hip/hip_runtime.h>
#include <math.h>

// ---------------------------------------------------------------------------
// GATRefiner: 3-layer GAT on MI355X.
// GEMMs on matrix cores (split-bf16 A, bf16 weights, fused attention-coef
// epilogue). Aggregation: one-pass softmax (exp2 domain) over a CSR padded
// to 8-edge batches with a sentinel row; SOFTWARE-PIPELINED 2-deep so the
// next batch's gathers are in flight under the current batch's VALU.
// ---------------------------------------------------------------------------

typedef unsigned short ushort;
typedef __attribute__((ext_vector_type(8))) short bf16x8;   // 8 bf16 = 4 VGPR
typedef __attribute__((ext_vector_type(4))) float f32x4;
typedef __attribute__((ext_vector_type(2))) float f32x2;

#define LOG2E 1.4426950408889634f

static __device__ __forceinline__ ushort f2bf(float f) {   // RNE float->bf16
    unsigned x = __float_as_uint(f);
    unsigned r = (x + 0x7FFF + ((x >> 16) & 1)) >> 16;
    return (ushort)r;
}
static __device__ __forceinline__ float bf2f(ushort u) {
    return __uint_as_float(((unsigned)u) << 16);
}

// ---------------- CSR construction ----------------

__global__ void count_deg(const int* __restrict__ ei, int E, int* __restrict__ deg) {
    int i = blockIdx.x * blockDim.x + threadIdx.x;
    int stride = gridDim.x * blockDim.x;
    for (int e = i; e < E; e += stride) {
        int d = ei[E + e];
        atomicAdd(&deg[d], 1);
    }
}

// scan of per-node PADDED segment size: ceil((deg+1)/8)*8
__global__ void scan_local(const int* __restrict__ deg, int* __restrict__ offsets,
                           int* __restrict__ blockSums, int N) {
    int tid = threadIdx.x;
    int lane = tid & 63;
    int wv = tid >> 6;
    int base = blockIdx.x * 1024 + tid * 4;
    int v[4];
#pragma unroll
    for (int j = 0; j < 4; ++j) {
        int idx = base + j;
        v[j] = (idx < N) ? ((deg[idx] + 1 + 7) & ~7) : 0;
    }
    int tsum = v[0] + v[1] + v[2] + v[3];
    int inc = tsum;
#pragma unroll
    for (int off = 1; off < 64; off <<= 1) {
        int u = __shfl_up(inc, off);
        if (lane >= off) inc += u;
    }
    __shared__ int wtot[4];
    if (lane == 63) wtot[wv] = inc;
    __syncthreads();
    int wbase = 0;
#pragma unroll
    for (int w = 0; w < 4; ++w)
        if (w < wv) wbase += wtot[w];
    int run = wbase + inc - tsum;
#pragma unroll
    for (int j = 0; j < 4; ++j) {
        int idx = base + j;
        if (idx < N) offsets[idx] = run;
        run += v[j];
    }
    if (tid == 255) blockSums[blockIdx.x] = wbase + inc;
}

__global__ void scan_blocks(const int* __restrict__ blockSums, int* __restrict__ blockBase,
                            int* __restrict__ offsets, int N, int nblk) {
    int lane = threadIdx.x & 63;
    int v = (lane < nblk) ? blockSums[lane] : 0;
    int inc = v;
#pragma unroll
    for (int off = 1; off < 64; off <<= 1) {
        int u = __shfl_up(inc, off);
        if (lane >= off) inc += u;
    }
    if (lane < nblk) blockBase[lane] = inc - v;
    if (lane == 63) offsets[N] = inc;
}

__global__ void fill_sent(int* __restrict__ csr_src, int cap, int N) {
    int i = blockIdx.x * blockDim.x + threadIdx.x;
    if (i < cap) csr_src[i] = N;
}

// offsets += blockBase; self-loop into slot 0; counter = 1  (fused)
__global__ void scan_add_fill(int* __restrict__ offsets, const int* __restrict__ blockBase,
                              int* __restrict__ counter, int* __restrict__ csr_src, int N) {
    int i = blockIdx.x * blockDim.x + threadIdx.x;
    if (i < N) {
        int o = offsets[i] + blockBase[i >> 10];
        offsets[i] = o;
        csr_src[o] = i;
        counter[i] = 1;
    }
}

__global__ void fill_edges(const int* __restrict__ ei, int E,
                           const int* __restrict__ offsets, int* __restrict__ counter,
                           int* __restrict__ csr_src) {
    int i = blockIdx.x * blockDim.x + threadIdx.x;
    int stride = gridDim.x * blockDim.x;
    for (int e = i; e < E; e += stride) {
        int s = ei[e];
        int d = ei[E + e];
        int pos = offsets[d] + atomicAdd(&counter[d], 1);
        csr_src[pos] = s;
    }
}

// ---------------- split / prep helpers ----------------

__global__ void xsplit(const float* __restrict__ X, ushort* __restrict__ Xh,
                       ushort* __restrict__ Xl, int total4) {
    int i = blockIdx.x * blockDim.x + threadIdx.x;
    if (i >= total4) return;
    float4 v = *(const float4*)(X + (size_t)i * 4);
    ushort4 h, l;
    h.x = f2bf(v.x); l.x = f2bf(v.x - bf2f(h.x));
    h.y = f2bf(v.y); l.y = f2bf(v.y - bf2f(h.y));
    h.z = f2bf(v.z); l.z = f2bf(v.z - bf2f(h.z));
    h.w = f2bf(v.w); l.w = f2bf(v.w - bf2f(h.w));
    *(ushort4*)(Xh + (size_t)i * 4) = h;
    *(ushort4*)(Xl + (size_t)i * 4) = l;
}

// fused: W1t/W2t/W3t transpose+round, sentinel rows (hb=0, e_s=-1e30)
__global__ void prep_misc(const float* __restrict__ W1, const float* __restrict__ W2,
                          const float* __restrict__ W3,
                          ushort* __restrict__ W1t, ushort* __restrict__ W2t,
                          ushort* __restrict__ W3t,
                          ushort* __restrict__ hb, float* __restrict__ e_s4,
                          float* __restrict__ e_s3, int N) {
    int id = blockIdx.x * blockDim.x + threadIdx.x;
    if (id < 32768) {                         // W1: K=128, N=256
        int k = id % 128, n = id / 128;
        W1t[id] = f2bf(W1[(size_t)k * 256 + n]);
        return;
    }
    id -= 32768;
    if (id < 65536) {                         // W2: K=256, N=256
        int k = id % 256, n = id / 256;
        W2t[id] = f2bf(W2[(size_t)k * 256 + n]);
        return;
    }
    id -= 65536;
    if (id < 16384) {                         // W3: K=256, N=64
        int k = id % 256, n = id / 256;
        W3t[id] = f2bf(W3[(size_t)k * 64 + n]);
        return;
    }
    id -= 16384;
    if (id < 64) {                            // hb sentinel row (512B layout)
        ushort4 z = {0, 0, 0, 0};
        *(ushort4*)(hb + (size_t)N * 256 + id * 4) = z;
        return;
    }
    id -= 64;
    if (id < 4) { e_s4[(size_t)N * 4 + id] = -1e30f; return; }
    id -= 4;
    if (id == 0) e_s3[N] = -1e30f;
}

// ---------------- MFMA GEMM + fused attention coefficients ----------------
// Cb(bf16) = round((Ah+Al) @ Bt^T); epilogue also emits e_s/e_d (xLOG2E).
// Requires BN == full N (grid.y == 1). WN==H: one head per wave (shfl
// reduce). H==1: LDS reduce across column-waves + zero 128B sentinel row.
// C/D frag layout: col=lane&15, row=(lane>>4)*4+j (verified m89/m91).

template<int BM, int BN, int WM, int WN, int THREADS, int H>
__global__ __launch_bounds__(THREADS) void gemm_mfma(const ushort* __restrict__ Ah,
                                                     const ushort* __restrict__ Al,
                                                     const ushort* __restrict__ Bh,
                                                     ushort* __restrict__ Cb,
                                                     float* __restrict__ e_s,
                                                     float* __restrict__ e_d,
                                                     const float* __restrict__ a_src,
                                                     const float* __restrict__ a_dst,
                                                     int M, int N, int K) {
    constexpr int BK = 32, PAD = 8;
    constexpr int MI = BM / WM / 16;
    constexpr int NI = BN / WN / 16;
    static_assert(WM * WN * 64 == THREADS, "wave grid mismatch");
    __shared__ ushort As[2][BM][BK + PAD];
    __shared__ ushort Bs[BN][BK + PAD];

    int tid = threadIdx.x;
    int lane = tid & 63;
    int wid = tid >> 6;
    int fr = lane & 15;
    int fg = lane >> 4;
    int wm0 = (wid / WN) * (BM / WM);
    int wn0 = (wid % WN) * (BN / WN);
    int mBase = blockIdx.x * BM;
    int nBase = blockIdx.y * BN;

    f32x4 acc[MI][NI];
#pragma unroll
    for (int mi = 0; mi < MI; ++mi)
#pragma unroll
        for (int ni = 0; ni < NI; ++ni) acc[mi][ni] = (f32x4)0.0f;

    constexpr int ACH = BM * BK / 8;
    constexpr int BCH = BN * BK / 8;

    const int KI = K / BK;
    for (int t = 0; t < KI; ++t) {
        int k0 = t * BK;
        for (int q = tid; q < ACH; q += THREADS) {
            int row = q >> 2;
            int sl = (q & 3) * 8;
            int gm = mBase + row;
            if (gm >= M) gm = M - 1;
            size_t off = (size_t)gm * K + k0 + sl;
            *(bf16x8*)&As[0][row][sl] = *(const bf16x8*)(Ah + off);
            *(bf16x8*)&As[1][row][sl] = *(const bf16x8*)(Al + off);
        }
        for (int q = tid; q < BCH; q += THREADS) {
            int row = q >> 2;
            int sl = (q & 3) * 8;
            size_t off = (size_t)(nBase + row) * K + k0 + sl;
            *(bf16x8*)&Bs[row][sl] = *(const bf16x8*)(Bh + off);
        }
        __syncthreads();

        bf16x8 afh[MI], afl[MI], bfh[NI];
#pragma unroll
        for (int mi = 0; mi < MI; ++mi) {
            afh[mi] = *(const bf16x8*)&As[0][wm0 + mi * 16 + fr][fg * 8];
            afl[mi] = *(const bf16x8*)&As[1][wm0 + mi * 16 + fr][fg * 8];
        }
#pragma unroll
        for (int ni = 0; ni < NI; ++ni)
            bfh[ni] = *(const bf16x8*)&Bs[wn0 + ni * 16 + fr][fg * 8];
#pragma unroll
        for (int mi = 0; mi < MI; ++mi)
#pragma unroll
            for (int ni = 0; ni < NI; ++ni) {
                acc[mi][ni] = __builtin_amdgcn_mfma_f32_16x16x32_bf16(
                    afh[mi], bfh[ni], acc[mi][ni], 0, 0, 0);
                acc[mi][ni] = __builtin_amdgcn_mfma_f32_16x16x32_bf16(
                    afl[mi], bfh[ni], acc[mi][ni], 0, 0, 0);
            }
        __syncthreads();
    }

    // ---- C write (bf16) ----
#pragma unroll
    for (int mi = 0; mi < MI; ++mi) {
#pragma unroll
        for (int j = 0; j < 4; ++j) {
            int gm = mBase + wm0 + mi * 16 + fg * 4 + j;
            if (gm >= M) continue;
#pragma unroll
            for (int ni = 0; ni < NI; ++ni) {
                int gn = nBase + wn0 + ni * 16 + fr;
                Cb[(size_t)gm * N + gn] = f2bf(acc[mi][ni][j]);
            }
        }
    }

    // ---- fused attention coefficients ----
    float asv[NI], adv[NI];
#pragma unroll
    for (int ni = 0; ni < NI; ++ni) {
        int col = wn0 + ni * 16 + fr;
        asv[ni] = a_src[col];
        adv[ni] = a_dst[col];
    }
    if constexpr (WN == H) {
        const int head = wn0 / (BN / H);
#pragma unroll
        for (int mi = 0; mi < MI; ++mi) {
#pragma unroll
            for (int j = 0; j < 4; ++j) {
                float ps = 0.0f, pd = 0.0f;
#pragma unroll
                for (int ni = 0; ni < NI; ++ni) {
                    ps += acc[mi][ni][j] * asv[ni];
                    pd += acc[mi][ni][j] * adv[ni];
                }
#pragma unroll
                for (int off = 1; off <= 8; off <<= 1) {
                    ps += __shfl_xor(ps, off);
                    pd += __shfl_xor(pd, off);
                }
                int gm = mBase + wm0 + mi * 16 + fg * 4 + j;
                if (fr == 0 && gm < M) {
                    e_s[(size_t)gm * H + head] = ps * LOG2E;
                    e_d[(size_t)gm * H + head] = pd * LOG2E;
                }
            }
        }
    } else {
        __shared__ float esb[WN][BM];
        __shared__ float edb[WN][BM];
        int wc = wid % WN;
#pragma unroll
        for (int mi = 0; mi < MI; ++mi) {
#pragma unroll
            for (int j = 0; j < 4; ++j) {
                float ps = 0.0f, pd = 0.0f;
#pragma unroll
                for (int ni = 0; ni < NI; ++ni) {
                    ps += acc[mi][ni][j] * asv[ni];
                    pd += acc[mi][ni][j] * adv[ni];
                }
#pragma unroll
                for (int off = 1; off <= 8; off <<= 1) {
                    ps += __shfl_xor(ps, off);
                    pd += __shfl_xor(pd, off);
                }
                if (fr == 0) {
                    int lr = wm0 + mi * 16 + fg * 4 + j;
                    esb[wc][lr] = ps;
                    edb[wc][lr] = pd;
                }
            }
        }
        __syncthreads();
        if (tid < BM) {
            int gm = mBase + tid;
            if (gm < M) {
                float ps = 0.0f, pd = 0.0f;
#pragma unroll
                for (int wcc = 0; wcc < WN; ++wcc) {
                    ps += esb[wcc][tid];
                    pd += edb[wcc][tid];
                }
                e_s[gm] = ps * LOG2E;
                e_d[gm] = pd * LOG2E;
            }
        }
        if (blockIdx.x == 0 && tid < 16) {
            ushort4 z = {0, 0, 0, 0};
            *(ushort4*)(Cb + (size_t)M * N + tid * 4) = z;
        }
    }
}

// ---------------- aggregation: 2-deep pipelined one-pass softmax -----------
// Segments multiples of 8 with sentinel pads (p==0 exactly). Two register
// batch-buffers alternate: LOAD(next) issues its gathers before COMPUTE
// (current) so ~2 batches are in flight per wave. exp2 domain.
// leaky(t) == fmax(t, 0.2t). bf16 pairs unpacked via shl/and into f32x2 FMAs.

#define AGG_LOAD(S, kk)                                                        \
    do {                                                                       \
        int4 q0 = *(const int4*)(csr_src + (kk));                              \
        int4 q1 = *(const int4*)(csr_src + (kk) + 4);                          \
        int sx[8] = {q0.x, q0.y, q0.z, q0.w, q1.x, q1.y, q1.z, q1.w};          \
        _Pragma("unroll")                                                      \
        for (int u = 0; u < 8; ++u)                                            \
            eb##S[u] = *(const float*)(esB + (((unsigned)(sx[u] * H + hd)) << 2)); \
        if constexpr (VEC == 4) {                                              \
            _Pragma("unroll")                                                  \
            for (int u = 0; u < 8; ++u)                                        \
                hv##S[u] = *(const uint2*)(hbB + (((unsigned)sx[u]) << ROWSH) + laneOff); \
        } else {                                                               \
            _Pragma("unroll")                                                  \
            for (int u = 0; u < 8; ++u)                                        \
                hs##S[u] = *(const ushort*)(hbB + (((unsigned)sx[u]) << ROWSH) + laneOff); \
        }                                                                      \
    } while (0)

#define AGG_COMPUTE(S)                                                         \
    do {                                                                       \
        float p[8];                                                            \
        float ps = 0.0f;                                                       \
        _Pragma("unroll")                                                      \
        for (int u = 0; u < 8; ++u) {                                          \
            float t = eb##S[u] + ed;                                           \
            t = fmaxf(t, 0.2f * t);                                            \
            p[u] = __builtin_amdgcn_exp2f(t);                                  \
            ps += p[u];                                                        \
        }                                                                      \
        s += ps;                                                               \
        if constexpr (VEC == 4) {                                              \
            _Pragma("unroll")                                                  \
            for (int u = 0; u < 8; ++u) {                                      \
                uint2 wv_ = hv##S[u];                                          \
                f32x2 a_, b_;                                                  \
                a_[0] = __uint_as_float(wv_.x << 16);                          \
                a_[1] = __uint_as_float(wv_.x & 0xffff0000u);                  \
                b_[0] = __uint_as_float(wv_.y << 16);                          \
                b_[1] = __uint_as_float(wv_.y & 0xffff0000u);                  \
                acc01 += p[u] * a_;                                            \
                acc23 += p[u] * b_;                                            \
            }                                                                  \
        } else {                                                               \
            _Pragma("unroll")                                                  \
            for (int u = 0; u < 8; ++u)                                        \
                acc0 += p[u] * bf2f(hs##S[u]);                                 \
        }                                                                      \
    } while (0)

template<int HC, int H, bool ELU, bool SPLIT, bool CLS>
__global__ void aggregate(const ushort* __restrict__ hb,
                          const float* __restrict__ e_s, const float* __restrict__ e_d,
                          const int* __restrict__ offsets, const int* __restrict__ csr_src,
                          const float* __restrict__ bias,
                          float* __restrict__ out,
                          ushort* __restrict__ oh, ushort* __restrict__ ol,
                          const float* __restrict__ clsW, const float* __restrict__ clsB,
                          float* __restrict__ outN, int N) {
    int wid = (int)((blockIdx.x * (size_t)blockDim.x + threadIdx.x) >> 6);
    int lane = threadIdx.x & 63;
    if (wid >= N) return;
    constexpr int VEC = HC / 64;
    constexpr int C = HC / H;
    constexpr int ROWSH = (HC == 256) ? 9 : 7;
    int hd = (lane * VEC) / C;
    float ed = e_d[(size_t)wid * H + hd];
    int beg = offsets[wid], end = offsets[wid + 1];
    const char* hbB = (const char*)hb;
    const char* esB = (const char*)e_s;
    unsigned laneOff = (unsigned)lane * (VEC * 2);

    float s = 0.0f;
    f32x2 acc01 = {0.0f, 0.0f}, acc23 = {0.0f, 0.0f};
    float acc0 = 0.0f;

    float eb0[8], eb1[8];
    uint2 hv0[8], hv1[8];
    ushort hs0[8], hs1[8];

    // 2-deep software pipeline (segments always >= 1 batch)
    AGG_LOAD(0, beg);
    int k = beg;
    while (true) {
        int kn = k + 8;
        if (kn < end) {
            AGG_LOAD(1, kn);
            AGG_COMPUTE(0);
            k = kn;
            kn += 8;
            if (kn < end) {
                AGG_LOAD(0, kn);
                AGG_COMPUTE(1);
                k = kn;
            } else {
                AGG_COMPUTE(1);
                break;
            }
        } else {
            AGG_COMPUTE(0);
            break;
        }
    }

    float inv = 1.0f / (s + 1e-16f);
    float o[VEC];
    if constexpr (VEC == 4) {
        o[0] = acc01[0]; o[1] = acc01[1]; o[2] = acc23[0]; o[3] = acc23[1];
    } else {
        o[0] = acc0;
    }
#pragma unroll
    for (int j = 0; j < VEC; ++j) {
        int f = lane * VEC + j;
        o[j] = o[j] * inv + bias[f];
        if constexpr (ELU) o[j] = (o[j] > 0.0f) ? o[j] : expm1f(o[j]);
    }
    if constexpr (SPLIT) {
        if constexpr (VEC == 4) {
            ushort4 h4, l4;
            h4.x = f2bf(o[0]); l4.x = f2bf(o[0] - bf2f(h4.x));
            h4.y = f2bf(o[1]); l4.y = f2bf(o[1] - bf2f(h4.y));
            h4.z = f2bf(o[2]); l4.z = f2bf(o[2] - bf2f(h4.z));
            h4.w = f2bf(o[3]); l4.w = f2bf(o[3] - bf2f(h4.w));
            *(ushort4*)(oh + (size_t)wid * HC + lane * 4) = h4;
            *(ushort4*)(ol + (size_t)wid * HC + lane * 4) = l4;
        } else {
            ushort h1 = f2bf(o[0]);
            oh[(size_t)wid * HC + lane] = h1;
            ol[(size_t)wid * HC + lane] = f2bf(o[0] - bf2f(h1));
        }
    } else {
#pragma unroll
        for (int j = 0; j < VEC; ++j)
            out[(size_t)wid * HC + lane * VEC + j] = o[j];
    }
    if constexpr (CLS) {
        float p0 = o[0] * clsW[lane * 2 + 0];
        float p1 = o[0] * clsW[lane * 2 + 1];
#pragma unroll
        for (int off = 1; off <= 32; off <<= 1) {
            p0 += __shfl_xor(p0, off);
            p1 += __shfl_xor(p1, off);
        }
        if (lane == 0) {
            outN[(size_t)wid * 2 + 0] = p0 + clsB[0];
            outN[(size_t)wid * 2 + 1] = p1 + clsB[1];
        }
    }
}

// ---------------------------------------------------------------------------

extern "C" void kernel_launch(void* const* d_in, const int* in_sizes, int n_in,
                              void* d_out, int out_size, void* d_ws, size_t ws_size,
                              hipStream_t stream) {
    const float* x      = (const float*)d_in[0];
    const int*   ei     = (const int*)d_in[1];
    const float* W1     = (const float*)d_in[2];
    const float* a1_src = (const float*)d_in[3];
    const float* a1_dst = (const float*)d_in[4];
    const float* b1     = (const float*)d_in[5];
    const float* W2     = (const float*)d_in[6];
    const float* a2_src = (const float*)d_in[7];
    const float* a2_dst = (const float*)d_in[8];
    const float* b2     = (const float*)d_in[9];
    const float* W3     = (const float*)d_in[10];
    const float* a3_src = (const float*)d_in[11];
    const float* a3_dst = (const float*)d_in[12];
    const float* b3     = (const float*)d_in[13];
    const float* cls_W  = (const float*)d_in[14];
    const float* cls_b  = (const float*)d_in[15];

    const int N = in_sizes[0] / 128;     // 50000
    const int E = in_sizes[1] / 2;       // 800000
    const int ETcap = E + 8 * N + 64;    // padded CSR capacity bound
    const int HC = 256;
    const int nScanBlk = (N + 1023) / 1024;

    // ---- workspace carve-up (256B aligned) ----
    char* w = (char*)d_ws;
    auto carve = [&](size_t bytes) {
        char* p = w;
        w += (bytes + 255) & ~(size_t)255;
        return p;
    };
    int*    deg     = (int*)   carve((size_t)N * 4);
    int*    counter = (int*)   carve((size_t)N * 4);
    int*    offsets = (int*)   carve((size_t)(N + 1) * 4);
    int*    csr_src = (int*)   carve((size_t)ETcap * 4);
    int*    blkSums = (int*)   carve((size_t)64 * 4);
    int*    blkBase = (int*)   carve((size_t)64 * 4);
    float*  e_s     = (float*) carve((size_t)(N + 1) * 4 * 4);   // H=4 + sentinel
    float*  e_d     = (float*) carve((size_t)N * 4 * 4);
    float*  e_s3    = (float*) carve((size_t)(N + 1) * 4);       // H=1 + sentinel
    float*  e_d3    = (float*) carve((size_t)N * 4);
    ushort* hb      = (ushort*)carve((size_t)(N + 1) * HC * 2);  // + sentinel row
    ushort* Ahi     = (ushort*)carve((size_t)N * HC * 2);
    ushort* Alo     = (ushort*)carve((size_t)N * HC * 2);
    ushort* W1t     = (ushort*)carve((size_t)128 * 256 * 2);
    ushort* W2t     = (ushort*)carve((size_t)256 * 256 * 2);
    ushort* W3t     = (ushort*)carve((size_t)256 * 64 * 2);
    (void)ws_size;

    float* out_node = (float*)d_out;                  // [N,2]
    float* out_link = (float*)d_out + 2 * (size_t)N;  // [N,64]

    // ---- CSR build (padded to 8-edge batches, sentinel = N) ----
    hipMemsetAsync(deg, 0, (size_t)N * 4, stream);
    int eblocks = (E + 255) / 256;
    if (eblocks > 2048) eblocks = 2048;
    count_deg<<<eblocks, 256, 0, stream>>>(ei, E, deg);
    scan_local<<<nScanBlk, 256, 0, stream>>>(deg, offsets, blkSums, N);
    scan_blocks<<<1, 64, 0, stream>>>(blkSums, blkBase, offsets, N, nScanBlk);
    fill_sent<<<(ETcap + 255) / 256, 256, 0, stream>>>(csr_src, ETcap, N);
    scan_add_fill<<<(N + 255) / 256, 256, 0, stream>>>(offsets, blkBase, counter, csr_src, N);
    fill_edges<<<eblocks, 256, 0, stream>>>(ei, E, offsets, counter, csr_src);

    // ---- input / weight prep + sentinels ----
    xsplit<<<(N * 128 / 4 + 255) / 256, 256, 0, stream>>>(x, Ahi, Alo, N * 128 / 4);
    prep_misc<<<(32768 + 65536 + 16384 + 69 + 255) / 256, 256, 0, stream>>>(
        W1, W2, W3, W1t, W2t, W3t, hb, e_s, e_s3, N);

    dim3 g12((N + 63) / 64, 1);     // BM=64, BN=256
    dim3 g3((N + 63) / 64, 1);      // BM=64, BN=64
    int nodeBlocks = (N + 3) / 4;

    // ---- layer 1: 128 -> 4x64 ----
    gemm_mfma<64, 256, 2, 4, 512, 4><<<g12, 512, 0, stream>>>(
        Ahi, Alo, W1t, hb, e_s, e_d, a1_src, a1_dst, N, 256, 128);
    aggregate<256, 4, true, true, false><<<nodeBlocks, 256, 0, stream>>>(
        hb, e_s, e_d, offsets, csr_src, b1, nullptr, Ahi, Alo,
        nullptr, nullptr, nullptr, N);
    // ---- layer 2: 256 -> 4x64 ----
    gemm_mfma<64, 256, 2, 4, 512, 4><<<g12, 512, 0, stream>>>(
        Ahi, Alo, W2t, hb, e_s, e_d, a2_src, a2_dst, N, 256, 256);
    aggregate<256, 4, true, true, false><<<nodeBlocks, 256, 0, stream>>>(
        hb, e_s, e_d, offsets, csr_src, b2, nullptr, Ahi, Alo,
        nullptr, nullptr, nullptr, N);
    // ---- layer 3: 256 -> 64 (1 head, mean==identity, fused cls head) ----
    gemm_mfma<64, 64, 4, 2, 512, 1><<<g3, 512, 0, stream>>>(
        Ahi, Alo, W3t, hb, e_s3, e_d3, a3_src, a3_dst, N, 64, 256);
    aggregate<64, 1, false, false, true><<<nodeBlocks, 256, 0, stream>>>(
        hb, e_s3, e_d3, offsets, csr_src, b3, out_link, nullptr, nullptr,
        cls_W, cls_b, out_node, N);
}

// Round 11
// 348.424 us; speedup vs baseline: 1.0824x; 1.0824x over previous
//
#include <hip/hip_runtime.h>
#include <math.h>

// ---------------------------------------------------------------------------
// GATRefiner: 3-layer GAT on MI355X.
// GEMMs on matrix cores (split-bf16 A, bf16 weights, fused attention-coef
// epilogue, bf16 h output). Aggregation: one-pass softmax (exp2 domain) over
// a CSR padded to 8-edge batches with a sentinel row (p==0 exactly), bf16
// row gathers, fp32 accum; layer-3 epilogue fuses the classification head.
// r10 lesson: 2-deep SW pipeline doubled VGPRs, halved occupancy, regressed
// -- the simple loop at ~6 waves/SIMD is near the gather-pattern's memory
// saturation point. Keep 32-VGPR aggregate.
// ---------------------------------------------------------------------------

typedef unsigned short ushort;
typedef __attribute__((ext_vector_type(8))) short bf16x8;   // 8 bf16 = 4 VGPR
typedef __attribute__((ext_vector_type(4))) float f32x4;

#define LOG2E 1.4426950408889634f

static __device__ __forceinline__ ushort f2bf(float f) {   // RNE float->bf16
    unsigned x = __float_as_uint(f);
    unsigned r = (x + 0x7FFF + ((x >> 16) & 1)) >> 16;
    return (ushort)r;
}
static __device__ __forceinline__ float bf2f(ushort u) {
    return __uint_as_float(((unsigned)u) << 16);
}

// ---------------- CSR construction ----------------

__global__ void count_deg(const int* __restrict__ ei, int E, int* __restrict__ deg) {
    int i = blockIdx.x * blockDim.x + threadIdx.x;
    int stride = gridDim.x * blockDim.x;
    for (int e = i; e < E; e += stride) {
        int d = ei[E + e];
        atomicAdd(&deg[d], 1);
    }
}

// scan of per-node PADDED segment size: ceil((deg+1)/8)*8
__global__ void scan_local(const int* __restrict__ deg, int* __restrict__ offsets,
                           int* __restrict__ blockSums, int N) {
    int tid = threadIdx.x;
    int lane = tid & 63;
    int wv = tid >> 6;
    int base = blockIdx.x * 1024 + tid * 4;
    int v[4];
#pragma unroll
    for (int j = 0; j < 4; ++j) {
        int idx = base + j;
        v[j] = (idx < N) ? ((deg[idx] + 1 + 7) & ~7) : 0;
    }
    int tsum = v[0] + v[1] + v[2] + v[3];
    int inc = tsum;
#pragma unroll
    for (int off = 1; off < 64; off <<= 1) {
        int u = __shfl_up(inc, off);
        if (lane >= off) inc += u;
    }
    __shared__ int wtot[4];
    if (lane == 63) wtot[wv] = inc;
    __syncthreads();
    int wbase = 0;
#pragma unroll
    for (int w = 0; w < 4; ++w)
        if (w < wv) wbase += wtot[w];
    int run = wbase + inc - tsum;
#pragma unroll
    for (int j = 0; j < 4; ++j) {
        int idx = base + j;
        if (idx < N) offsets[idx] = run;
        run += v[j];
    }
    if (tid == 255) blockSums[blockIdx.x] = wbase + inc;
}

__global__ void scan_blocks(const int* __restrict__ blockSums, int* __restrict__ blockBase,
                            int* __restrict__ offsets, int N, int nblk) {
    int lane = threadIdx.x & 63;
    int v = (lane < nblk) ? blockSums[lane] : 0;
    int inc = v;
#pragma unroll
    for (int off = 1; off < 64; off <<= 1) {
        int u = __shfl_up(inc, off);
        if (lane >= off) inc += u;
    }
    if (lane < nblk) blockBase[lane] = inc - v;
    if (lane == 63) offsets[N] = inc;
}

// offsets += blockBase; self-loop into slot 0; counter = 1; write the <=7
// pad slots of this node's segment with sentinel N (no full-capacity sweep).
__global__ void scan_add_fill(int* __restrict__ offsets, const int* __restrict__ blockBase,
                              const int* __restrict__ deg, int* __restrict__ counter,
                              int* __restrict__ csr_src, int N) {
    int i = blockIdx.x * blockDim.x + threadIdx.x;
    if (i >= N) return;
    int o = offsets[i] + blockBase[i >> 10];
    offsets[i] = o;
    csr_src[o] = i;
    counter[i] = 1;
    int d1 = deg[i] + 1;                 // real entries (incl. self loop)
    int size = (d1 + 7) & ~7;            // padded segment size
    for (int k = d1; k < size; ++k) csr_src[o + k] = N;
}

__global__ void fill_edges(const int* __restrict__ ei, int E,
                           const int* __restrict__ offsets, int* __restrict__ counter,
                           int* __restrict__ csr_src) {
    int i = blockIdx.x * blockDim.x + threadIdx.x;
    int stride = gridDim.x * blockDim.x;
    for (int e = i; e < E; e += stride) {
        int s = ei[e];
        int d = ei[E + e];
        int pos = offsets[d] + atomicAdd(&counter[d], 1);
        csr_src[pos] = s;
    }
}

// ---------------- fused prep: x split + weight transpose + sentinels -------
// id ranges: [0, X4)               xsplit (float4 granules of x)
//            [X4, +32768)          W1t (K=128,N=256)
//            [.., +65536)          W2t (K=256,N=256)
//            [.., +16384)          W3t (K=256,N=64)
//            [.., +64)             hb sentinel row (512B layout) = 0
//            [.., +4)              e_s4 sentinel = -1e30
//            [.., +1)              e_s3 sentinel = -1e30

__global__ void prep_all(const float* __restrict__ X, ushort* __restrict__ Xh,
                         ushort* __restrict__ Xl, int X4,
                         const float* __restrict__ W1, const float* __restrict__ W2,
                         const float* __restrict__ W3,
                         ushort* __restrict__ W1t, ushort* __restrict__ W2t,
                         ushort* __restrict__ W3t,
                         ushort* __restrict__ hb, float* __restrict__ e_s4,
                         float* __restrict__ e_s3, int N) {
    int id = blockIdx.x * blockDim.x + threadIdx.x;
    if (id < X4) {
        float4 v = *(const float4*)(X + (size_t)id * 4);
        ushort4 h, l;
        h.x = f2bf(v.x); l.x = f2bf(v.x - bf2f(h.x));
        h.y = f2bf(v.y); l.y = f2bf(v.y - bf2f(h.y));
        h.z = f2bf(v.z); l.z = f2bf(v.z - bf2f(h.z));
        h.w = f2bf(v.w); l.w = f2bf(v.w - bf2f(h.w));
        *(ushort4*)(Xh + (size_t)id * 4) = h;
        *(ushort4*)(Xl + (size_t)id * 4) = l;
        return;
    }
    id -= X4;
    if (id < 32768) {                         // W1t
        int k = id % 128, n = id / 128;
        W1t[id] = f2bf(W1[(size_t)k * 256 + n]);
        return;
    }
    id -= 32768;
    if (id < 65536) {                         // W2t
        int k = id % 256, n = id / 256;
        W2t[id] = f2bf(W2[(size_t)k * 256 + n]);
        return;
    }
    id -= 65536;
    if (id < 16384) {                         // W3t
        int k = id % 256, n = id / 256;
        W3t[id] = f2bf(W3[(size_t)k * 64 + n]);
        return;
    }
    id -= 16384;
    if (id < 64) {                            // hb sentinel row
        ushort4 z = {0, 0, 0, 0};
        *(ushort4*)(hb + (size_t)N * 256 + id * 4) = z;
        return;
    }
    id -= 64;
    if (id < 4) { e_s4[(size_t)N * 4 + id] = -1e30f; return; }
    id -= 4;
    if (id == 0) e_s3[N] = -1e30f;
}

// ---------------- MFMA GEMM + fused attention coefficients ----------------
// Cb(bf16) = round((Ah+Al) @ Bt^T); epilogue also emits e_s/e_d (xLOG2E).
// Requires BN == full N (grid.y == 1). WN==H: one head per wave (shfl
// reduce). H==1: LDS reduce across column-waves + zero 128B sentinel row.
// C/D frag layout: col=lane&15, row=(lane>>4)*4+j (verified m89/m91).

template<int BM, int BN, int WM, int WN, int THREADS, int H>
__global__ __launch_bounds__(THREADS) void gemm_mfma(const ushort* __restrict__ Ah,
                                                     const ushort* __restrict__ Al,
                                                     const ushort* __restrict__ Bh,
                                                     ushort* __restrict__ Cb,
                                                     float* __restrict__ e_s,
                                                     float* __restrict__ e_d,
                                                     const float* __restrict__ a_src,
                                                     const float* __restrict__ a_dst,
                                                     int M, int N, int K) {
    constexpr int BK = 32, PAD = 8;
    constexpr int MI = BM / WM / 16;
    constexpr int NI = BN / WN / 16;
    static_assert(WM * WN * 64 == THREADS, "wave grid mismatch");
    __shared__ ushort As[2][BM][BK + PAD];
    __shared__ ushort Bs[BN][BK + PAD];

    int tid = threadIdx.x;
    int lane = tid & 63;
    int wid = tid >> 6;
    int fr = lane & 15;
    int fg = lane >> 4;
    int wm0 = (wid / WN) * (BM / WM);
    int wn0 = (wid % WN) * (BN / WN);
    int mBase = blockIdx.x * BM;
    int nBase = blockIdx.y * BN;

    f32x4 acc[MI][NI];
#pragma unroll
    for (int mi = 0; mi < MI; ++mi)
#pragma unroll
        for (int ni = 0; ni < NI; ++ni) acc[mi][ni] = (f32x4)0.0f;

    constexpr int ACH = BM * BK / 8;
    constexpr int BCH = BN * BK / 8;

    const int KI = K / BK;
    for (int t = 0; t < KI; ++t) {
        int k0 = t * BK;
        for (int q = tid; q < ACH; q += THREADS) {
            int row = q >> 2;
            int sl = (q & 3) * 8;
            int gm = mBase + row;
            if (gm >= M) gm = M - 1;
            size_t off = (size_t)gm * K + k0 + sl;
            *(bf16x8*)&As[0][row][sl] = *(const bf16x8*)(Ah + off);
            *(bf16x8*)&As[1][row][sl] = *(const bf16x8*)(Al + off);
        }
        for (int q = tid; q < BCH; q += THREADS) {
            int row = q >> 2;
            int sl = (q & 3) * 8;
            size_t off = (size_t)(nBase + row) * K + k0 + sl;
            *(bf16x8*)&Bs[row][sl] = *(const bf16x8*)(Bh + off);
        }
        __syncthreads();

        bf16x8 afh[MI], afl[MI], bfh[NI];
#pragma unroll
        for (int mi = 0; mi < MI; ++mi) {
            afh[mi] = *(const bf16x8*)&As[0][wm0 + mi * 16 + fr][fg * 8];
            afl[mi] = *(const bf16x8*)&As[1][wm0 + mi * 16 + fr][fg * 8];
        }
#pragma unroll
        for (int ni = 0; ni < NI; ++ni)
            bfh[ni] = *(const bf16x8*)&Bs[wn0 + ni * 16 + fr][fg * 8];
#pragma unroll
        for (int mi = 0; mi < MI; ++mi)
#pragma unroll
            for (int ni = 0; ni < NI; ++ni) {
                acc[mi][ni] = __builtin_amdgcn_mfma_f32_16x16x32_bf16(
                    afh[mi], bfh[ni], acc[mi][ni], 0, 0, 0);
                acc[mi][ni] = __builtin_amdgcn_mfma_f32_16x16x32_bf16(
                    afl[mi], bfh[ni], acc[mi][ni], 0, 0, 0);
            }
        __syncthreads();
    }

    // ---- C write (bf16) ----
#pragma unroll
    for (int mi = 0; mi < MI; ++mi) {
#pragma unroll
        for (int j = 0; j < 4; ++j) {
            int gm = mBase + wm0 + mi * 16 + fg * 4 + j;
            if (gm >= M) continue;
#pragma unroll
            for (int ni = 0; ni < NI; ++ni) {
                int gn = nBase + wn0 + ni * 16 + fr;
                Cb[(size_t)gm * N + gn] = f2bf(acc[mi][ni][j]);
            }
        }
    }

    // ---- fused attention coefficients ----
    float asv[NI], adv[NI];
#pragma unroll
    for (int ni = 0; ni < NI; ++ni) {
        int col = wn0 + ni * 16 + fr;
        asv[ni] = a_src[col];
        adv[ni] = a_dst[col];
    }
    if constexpr (WN == H) {
        const int head = wn0 / (BN / H);
#pragma unroll
        for (int mi = 0; mi < MI; ++mi) {
#pragma unroll
            for (int j = 0; j < 4; ++j) {
                float ps = 0.0f, pd = 0.0f;
#pragma unroll
                for (int ni = 0; ni < NI; ++ni) {
                    ps += acc[mi][ni][j] * asv[ni];
                    pd += acc[mi][ni][j] * adv[ni];
                }
#pragma unroll
                for (int off = 1; off <= 8; off <<= 1) {
                    ps += __shfl_xor(ps, off);
                    pd += __shfl_xor(pd, off);
                }
                int gm = mBase + wm0 + mi * 16 + fg * 4 + j;
                if (fr == 0 && gm < M) {
                    e_s[(size_t)gm * H + head] = ps * LOG2E;
                    e_d[(size_t)gm * H + head] = pd * LOG2E;
                }
            }
        }
    } else {
        __shared__ float esb[WN][BM];
        __shared__ float edb[WN][BM];
        int wc = wid % WN;
#pragma unroll
        for (int mi = 0; mi < MI; ++mi) {
#pragma unroll
            for (int j = 0; j < 4; ++j) {
                float ps = 0.0f, pd = 0.0f;
#pragma unroll
                for (int ni = 0; ni < NI; ++ni) {
                    ps += acc[mi][ni][j] * asv[ni];
                    pd += acc[mi][ni][j] * adv[ni];
                }
#pragma unroll
                for (int off = 1; off <= 8; off <<= 1) {
                    ps += __shfl_xor(ps, off);
                    pd += __shfl_xor(pd, off);
                }
                if (fr == 0) {
                    int lr = wm0 + mi * 16 + fg * 4 + j;
                    esb[wc][lr] = ps;
                    edb[wc][lr] = pd;
                }
            }
        }
        __syncthreads();
        if (tid < BM) {
            int gm = mBase + tid;
            if (gm < M) {
                float ps = 0.0f, pd = 0.0f;
#pragma unroll
                for (int wcc = 0; wcc < WN; ++wcc) {
                    ps += esb[wcc][tid];
                    pd += edb[wcc][tid];
                }
                e_s[gm] = ps * LOG2E;
                e_d[gm] = pd * LOG2E;
            }
        }
        if (blockIdx.x == 0 && tid < 16) {
            ushort4 z = {0, 0, 0, 0};
            *(ushort4*)(Cb + (size_t)M * N + tid * 4) = z;
        }
    }
}

// ---------------- aggregation: padded one-pass softmax, bf16 gather --------
// Segments multiples of 8 with sentinel pads (p==0 exactly); exp2 domain;
// leaky(t) == fmax(t, 0.2t). Simple 32-VGPR loop (r10 pipeline regressed:
// VGPR 60 halved occupancy). CLS=true fuses the classification head.

template<int HC, int H, bool ELU, bool SPLIT, bool CLS>
__global__ void aggregate(const ushort* __restrict__ hb,
                          const float* __restrict__ e_s, const float* __restrict__ e_d,
                          const int* __restrict__ offsets, const int* __restrict__ csr_src,
                          const float* __restrict__ bias,
                          float* __restrict__ out,
                          ushort* __restrict__ oh, ushort* __restrict__ ol,
                          const float* __restrict__ clsW, const float* __restrict__ clsB,
                          float* __restrict__ outN, int N) {
    int wid = (int)((blockIdx.x * (size_t)blockDim.x + threadIdx.x) >> 6);
    int lane = threadIdx.x & 63;
    if (wid >= N) return;
    constexpr int VEC = HC / 64;
    constexpr int C = HC / H;
    constexpr int ROWSH = (HC == 256) ? 9 : 7;      // log2(row bytes)
    int hd = (lane * VEC) / C;
    float ed = e_d[(size_t)wid * H + hd];
    int beg = offsets[wid], end = offsets[wid + 1];
    const char* hbB = (const char*)hb;
    const char* esB = (const char*)e_s;
    unsigned laneOff = (unsigned)lane * (VEC * 2);

    float s = 0.0f;
    float acc[VEC];
#pragma unroll
    for (int j = 0; j < VEC; ++j) acc[j] = 0.0f;

    for (int k = beg; k < end; k += 8) {
        int4 c0 = *(const int4*)(csr_src + k);       // segments 8-aligned
        int4 c1 = *(const int4*)(csr_src + k + 4);
        int sidx[8] = {c0.x, c0.y, c0.z, c0.w, c1.x, c1.y, c1.z, c1.w};
        float e[8];
#pragma unroll
        for (int u = 0; u < 8; ++u)
            e[u] = *(const float*)(esB + (((unsigned)(sidx[u] * H + hd)) << 2));
        ushort4 hv4[8];
        ushort  hv1[8];
        if constexpr (VEC == 4) {
#pragma unroll
            for (int u = 0; u < 8; ++u)
                hv4[u] = *(const ushort4*)(hbB + (((unsigned)sidx[u]) << ROWSH) + laneOff);
        } else {
#pragma unroll
            for (int u = 0; u < 8; ++u)
                hv1[u] = *(const ushort*)(hbB + (((unsigned)sidx[u]) << ROWSH) + laneOff);
        }
        float p[8];
        float psum = 0.0f;
#pragma unroll
        for (int u = 0; u < 8; ++u) {
            float t = e[u] + ed;
            t = fmaxf(t, 0.2f * t);                   // leaky relu (log2-domain)
            p[u] = __builtin_amdgcn_exp2f(t);
            psum += p[u];
        }
        s += psum;
        if constexpr (VEC == 4) {
#pragma unroll
            for (int u = 0; u < 8; ++u) {
                acc[0] += p[u] * bf2f(hv4[u].x);
                acc[1] += p[u] * bf2f(hv4[u].y);
                acc[2] += p[u] * bf2f(hv4[u].z);
                acc[3] += p[u] * bf2f(hv4[u].w);
            }
        } else {
#pragma unroll
            for (int u = 0; u < 8; ++u) acc[0] += p[u] * bf2f(hv1[u]);
        }
    }
    float inv = 1.0f / (s + 1e-16f);
    float o[VEC];
#pragma unroll
    for (int j = 0; j < VEC; ++j) {
        int f = lane * VEC + j;
        o[j] = acc[j] * inv + bias[f];
        if constexpr (ELU) o[j] = (o[j] > 0.0f) ? o[j] : expm1f(o[j]);
    }
    if constexpr (SPLIT) {
        if constexpr (VEC == 4) {
            ushort4 h4, l4;
            h4.x = f2bf(o[0]); l4.x = f2bf(o[0] - bf2f(h4.x));
            h4.y = f2bf(o[1]); l4.y = f2bf(o[1] - bf2f(h4.y));
            h4.z = f2bf(o[2]); l4.z = f2bf(o[2] - bf2f(h4.z));
            h4.w = f2bf(o[3]); l4.w = f2bf(o[3] - bf2f(h4.w));
            *(ushort4*)(oh + (size_t)wid * HC + lane * 4) = h4;
            *(ushort4*)(ol + (size_t)wid * HC + lane * 4) = l4;
        } else {
            ushort h1 = f2bf(o[0]);
            oh[(size_t)wid * HC + lane] = h1;
            ol[(size_t)wid * HC + lane] = f2bf(o[0] - bf2f(h1));
        }
    } else {
#pragma unroll
        for (int j = 0; j < VEC; ++j)
            out[(size_t)wid * HC + lane * VEC + j] = o[j];
    }
    if constexpr (CLS) {
        float p0 = o[0] * clsW[lane * 2 + 0];
        float p1 = o[0] * clsW[lane * 2 + 1];
#pragma unroll
        for (int off = 1; off <= 32; off <<= 1) {
            p0 += __shfl_xor(p0, off);
            p1 += __shfl_xor(p1, off);
        }
        if (lane == 0) {
            outN[(size_t)wid * 2 + 0] = p0 + clsB[0];
            outN[(size_t)wid * 2 + 1] = p1 + clsB[1];
        }
    }
}

// ---------------------------------------------------------------------------

extern "C" void kernel_launch(void* const* d_in, const int* in_sizes, int n_in,
                              void* d_out, int out_size, void* d_ws, size_t ws_size,
                              hipStream_t stream) {
    const float* x      = (const float*)d_in[0];
    const int*   ei     = (const int*)d_in[1];
    const float* W1     = (const float*)d_in[2];
    const float* a1_src = (const float*)d_in[3];
    const float* a1_dst = (const float*)d_in[4];
    const float* b1     = (const float*)d_in[5];
    const float* W2     = (const float*)d_in[6];
    const float* a2_src = (const float*)d_in[7];
    const float* a2_dst = (const float*)d_in[8];
    const float* b2     = (const float*)d_in[9];
    const float* W3     = (const float*)d_in[10];
    const float* a3_src = (const float*)d_in[11];
    const float* a3_dst = (const float*)d_in[12];
    const float* b3     = (const float*)d_in[13];
    const float* cls_W  = (const float*)d_in[14];
    const float* cls_b  = (const float*)d_in[15];

    const int N = in_sizes[0] / 128;     // 50000
    const int E = in_sizes[1] / 2;       // 800000
    const int ETcap = E + 8 * N + 64;    // padded CSR capacity bound
    const int HC = 256;
    const int nScanBlk = (N + 1023) / 1024;

    // ---- workspace carve-up (256B aligned) ----
    char* w = (char*)d_ws;
    auto carve = [&](size_t bytes) {
        char* p = w;
        w += (bytes + 255) & ~(size_t)255;
        return p;
    };
    int*    deg     = (int*)   carve((size_t)N * 4);
    int*    counter = (int*)   carve((size_t)N * 4);
    int*    offsets = (int*)   carve((size_t)(N + 1) * 4);
    int*    csr_src = (int*)   carve((size_t)ETcap * 4);
    int*    blkSums = (int*)   carve((size_t)64 * 4);
    int*    blkBase = (int*)   carve((size_t)64 * 4);
    float*  e_s     = (float*) carve((size_t)(N + 1) * 4 * 4);   // H=4 + sentinel
    float*  e_d     = (float*) carve((size_t)N * 4 * 4);
    float*  e_s3    = (float*) carve((size_t)(N + 1) * 4);       // H=1 + sentinel
    float*  e_d3    = (float*) carve((size_t)N * 4);
    ushort* hb      = (ushort*)carve((size_t)(N + 1) * HC * 2);  // + sentinel row
    ushort* Ahi     = (ushort*)carve((size_t)N * HC * 2);
    ushort* Alo     = (ushort*)carve((size_t)N * HC * 2);
    ushort* W1t     = (ushort*)carve((size_t)128 * 256 * 2);
    ushort* W2t     = (ushort*)carve((size_t)256 * 256 * 2);
    ushort* W3t     = (ushort*)carve((size_t)256 * 64 * 2);
    (void)ws_size;

    float* out_node = (float*)d_out;                  // [N,2]
    float* out_link = (float*)d_out + 2 * (size_t)N;  // [N,64]

    // ---- CSR build (padded to 8-edge batches, sentinel = N) ----
    hipMemsetAsync(deg, 0, (size_t)N * 4, stream);
    int eblocks = (E + 255) / 256;
    if (eblocks > 2048) eblocks = 2048;
    count_deg<<<eblocks, 256, 0, stream>>>(ei, E, deg);
    scan_local<<<nScanBlk, 256, 0, stream>>>(deg, offsets, blkSums, N);
    scan_blocks<<<1, 64, 0, stream>>>(blkSums, blkBase, offsets, N, nScanBlk);
    scan_add_fill<<<(N + 255) / 256, 256, 0, stream>>>(offsets, blkBase, deg,
                                                       counter, csr_src, N);
    fill_edges<<<eblocks, 256, 0, stream>>>(ei, E, offsets, counter, csr_src);

    // ---- fused prep: x split + weight transposes + sentinel rows ----
    const int X4 = N * 128 / 4;
    const int prepTotal = X4 + 32768 + 65536 + 16384 + 64 + 4 + 1;
    prep_all<<<(prepTotal + 255) / 256, 256, 0, stream>>>(
        x, Ahi, Alo, X4, W1, W2, W3, W1t, W2t, W3t, hb, e_s, e_s3, N);

    dim3 g12((N + 63) / 64, 1);     // BM=64, BN=256
    dim3 g3((N + 63) / 64, 1);      // BM=64, BN=64
    int nodeBlocks = (N + 3) / 4;

    // ---- layer 1: 128 -> 4x64 ----
    gemm_mfma<64, 256, 2, 4, 512, 4><<<g12, 512, 0, stream>>>(
        Ahi, Alo, W1t, hb, e_s, e_d, a1_src, a1_dst, N, 256, 128);
    aggregate<256, 4, true, true, false><<<nodeBlocks, 256, 0, stream>>>(
        hb, e_s, e_d, offsets, csr_src, b1, nullptr, Ahi, Alo,
        nullptr, nullptr, nullptr, N);
    // ---- layer 2: 256 -> 4x64 ----
    gemm_mfma<64, 256, 2, 4, 512, 4><<<g12, 512, 0, stream>>>(
        Ahi, Alo, W2t, hb, e_s, e_d, a2_src, a2_dst, N, 256, 256);
    aggregate<256, 4, true, true, false><<<nodeBlocks, 256, 0, stream>>>(
        hb, e_s, e_d, offsets, csr_src, b2, nullptr, Ahi, Alo,
        nullptr, nullptr, nullptr, N);
    // ---- layer 3: 256 -> 64 (1 head, mean==identity, fused cls head) ----
    gemm_mfma<64, 64, 4, 2, 512, 1><<<g3, 512, 0, stream>>>(
        Ahi, Alo, W3t, hb, e_s3, e_d3, a3_src, a3_dst, N, 64, 256);
    aggregate<64, 1, false, false, true><<<nodeBlocks, 256, 0, stream>>>(
        hb, e_s3, e_d3, offsets, csr_src, b3, out_link, nullptr, nullptr,
        cls_W, cls_b, out_node, N);
}

// Round 12
// 343.006 us; speedup vs baseline: 1.0995x; 1.0158x over previous
//
#include <hip/hip_runtime.h>
#include <math.h>

// ---------------------------------------------------------------------------
// GATRefiner: 3-layer GAT on MI355X.
// GEMMs on matrix cores (split-bf16 A, bf16 weights, fused attention-coef
// epilogue, bf16 h output), 128-row tiles (r12: BM 64->128 doubles MFMA per
// staged byte). Aggregation: one-pass softmax (exp2 domain) over a CSR
// padded to 8-edge batches with a sentinel row, bf16 row gathers, fp32
// accum; layer-3 epilogue fuses the classification head.
// r10 lesson: SW pipelining the aggregate halves occupancy, regresses.
// r11 lesson: aggregate FETCH == 8 x hb-size (one sweep per XCD L2) -- the
// two big aggregates are at their structural floor (~75 us each).
// ---------------------------------------------------------------------------

typedef unsigned short ushort;
typedef __attribute__((ext_vector_type(8))) short bf16x8;   // 8 bf16 = 4 VGPR
typedef __attribute__((ext_vector_type(4))) float f32x4;

#define LOG2E 1.4426950408889634f

static __device__ __forceinline__ ushort f2bf(float f) {   // RNE float->bf16
    unsigned x = __float_as_uint(f);
    unsigned r = (x + 0x7FFF + ((x >> 16) & 1)) >> 16;
    return (ushort)r;
}
static __device__ __forceinline__ float bf2f(ushort u) {
    return __uint_as_float(((unsigned)u) << 16);
}

// ---------------- CSR construction ----------------

__global__ void count_deg(const int* __restrict__ ei, int E, int* __restrict__ deg) {
    int i = blockIdx.x * blockDim.x + threadIdx.x;
    int stride = gridDim.x * blockDim.x;
    for (int e = i; e < E; e += stride) {
        int d = ei[E + e];
        atomicAdd(&deg[d], 1);
    }
}

// scan of per-node PADDED segment size: ceil((deg+1)/8)*8
__global__ void scan_local(const int* __restrict__ deg, int* __restrict__ offsets,
                           int* __restrict__ blockSums, int N) {
    int tid = threadIdx.x;
    int lane = tid & 63;
    int wv = tid >> 6;
    int base = blockIdx.x * 1024 + tid * 4;
    int v[4];
#pragma unroll
    for (int j = 0; j < 4; ++j) {
        int idx = base + j;
        v[j] = (idx < N) ? ((deg[idx] + 1 + 7) & ~7) : 0;
    }
    int tsum = v[0] + v[1] + v[2] + v[3];
    int inc = tsum;
#pragma unroll
    for (int off = 1; off < 64; off <<= 1) {
        int u = __shfl_up(inc, off);
        if (lane >= off) inc += u;
    }
    __shared__ int wtot[4];
    if (lane == 63) wtot[wv] = inc;
    __syncthreads();
    int wbase = 0;
#pragma unroll
    for (int w = 0; w < 4; ++w)
        if (w < wv) wbase += wtot[w];
    int run = wbase + inc - tsum;
#pragma unroll
    for (int j = 0; j < 4; ++j) {
        int idx = base + j;
        if (idx < N) offsets[idx] = run;
        run += v[j];
    }
    if (tid == 255) blockSums[blockIdx.x] = wbase + inc;
}

__global__ void scan_blocks(const int* __restrict__ blockSums, int* __restrict__ blockBase,
                            int* __restrict__ offsets, int N, int nblk) {
    int lane = threadIdx.x & 63;
    int v = (lane < nblk) ? blockSums[lane] : 0;
    int inc = v;
#pragma unroll
    for (int off = 1; off < 64; off <<= 1) {
        int u = __shfl_up(inc, off);
        if (lane >= off) inc += u;
    }
    if (lane < nblk) blockBase[lane] = inc - v;
    if (lane == 63) offsets[N] = inc;
}

// offsets += blockBase; self-loop into slot 0; counter = 1; write the <=7
// pad slots of this node's segment with sentinel N (no full-capacity sweep).
__global__ void scan_add_fill(int* __restrict__ offsets, const int* __restrict__ blockBase,
                              const int* __restrict__ deg, int* __restrict__ counter,
                              int* __restrict__ csr_src, int N) {
    int i = blockIdx.x * blockDim.x + threadIdx.x;
    if (i >= N) return;
    int o = offsets[i] + blockBase[i >> 10];
    offsets[i] = o;
    csr_src[o] = i;
    counter[i] = 1;
    int d1 = deg[i] + 1;                 // real entries (incl. self loop)
    int size = (d1 + 7) & ~7;            // padded segment size
    for (int k = d1; k < size; ++k) csr_src[o + k] = N;
}

__global__ void fill_edges(const int* __restrict__ ei, int E,
                           const int* __restrict__ offsets, int* __restrict__ counter,
                           int* __restrict__ csr_src) {
    int i = blockIdx.x * blockDim.x + threadIdx.x;
    int stride = gridDim.x * blockDim.x;
    for (int e = i; e < E; e += stride) {
        int s = ei[e];
        int d = ei[E + e];
        int pos = offsets[d] + atomicAdd(&counter[d], 1);
        csr_src[pos] = s;
    }
}

// ---------------- fused prep: x split + weight transpose + sentinels -------

__global__ void prep_all(const float* __restrict__ X, ushort* __restrict__ Xh,
                         ushort* __restrict__ Xl, int X4,
                         const float* __restrict__ W1, const float* __restrict__ W2,
                         const float* __restrict__ W3,
                         ushort* __restrict__ W1t, ushort* __restrict__ W2t,
                         ushort* __restrict__ W3t,
                         ushort* __restrict__ hb, float* __restrict__ e_s4,
                         float* __restrict__ e_s3, int N) {
    int id = blockIdx.x * blockDim.x + threadIdx.x;
    if (id < X4) {
        float4 v = *(const float4*)(X + (size_t)id * 4);
        ushort4 h, l;
        h.x = f2bf(v.x); l.x = f2bf(v.x - bf2f(h.x));
        h.y = f2bf(v.y); l.y = f2bf(v.y - bf2f(h.y));
        h.z = f2bf(v.z); l.z = f2bf(v.z - bf2f(h.z));
        h.w = f2bf(v.w); l.w = f2bf(v.w - bf2f(h.w));
        *(ushort4*)(Xh + (size_t)id * 4) = h;
        *(ushort4*)(Xl + (size_t)id * 4) = l;
        return;
    }
    id -= X4;
    if (id < 32768) {                         // W1t (K=128,N=256)
        int k = id % 128, n = id / 128;
        W1t[id] = f2bf(W1[(size_t)k * 256 + n]);
        return;
    }
    id -= 32768;
    if (id < 65536) {                         // W2t (K=256,N=256)
        int k = id % 256, n = id / 256;
        W2t[id] = f2bf(W2[(size_t)k * 256 + n]);
        return;
    }
    id -= 65536;
    if (id < 16384) {                         // W3t (K=256,N=64)
        int k = id % 256, n = id / 256;
        W3t[id] = f2bf(W3[(size_t)k * 64 + n]);
        return;
    }
    id -= 16384;
    if (id < 64) {                            // hb sentinel row (512B layout)
        ushort4 z = {0, 0, 0, 0};
        *(ushort4*)(hb + (size_t)N * 256 + id * 4) = z;
        return;
    }
    id -= 64;
    if (id < 4) { e_s4[(size_t)N * 4 + id] = -1e30f; return; }
    id -= 4;
    if (id == 0) e_s3[N] = -1e30f;
}

// ---------------- MFMA GEMM + fused attention coefficients ----------------
// Cb(bf16) = round((Ah+Al) @ Bt^T); epilogue also emits e_s/e_d (xLOG2E).
// Requires BN == full N (grid.y == 1). WN==H: one head per wave (shfl
// reduce). H==1: LDS reduce across column-waves + zero 128B sentinel row.
// C/D frag layout: col=lane&15, row=(lane>>4)*4+j (verified m89/m91).

template<int BM, int BN, int WM, int WN, int THREADS, int H>
__global__ __launch_bounds__(THREADS) void gemm_mfma(const ushort* __restrict__ Ah,
                                                     const ushort* __restrict__ Al,
                                                     const ushort* __restrict__ Bh,
                                                     ushort* __restrict__ Cb,
                                                     float* __restrict__ e_s,
                                                     float* __restrict__ e_d,
                                                     const float* __restrict__ a_src,
                                                     const float* __restrict__ a_dst,
                                                     int M, int N, int K) {
    constexpr int BK = 32, PAD = 8;
    constexpr int MI = BM / WM / 16;
    constexpr int NI = BN / WN / 16;
    static_assert(WM * WN * 64 == THREADS, "wave grid mismatch");
    __shared__ ushort As[2][BM][BK + PAD];
    __shared__ ushort Bs[BN][BK + PAD];

    int tid = threadIdx.x;
    int lane = tid & 63;
    int wid = tid >> 6;
    int fr = lane & 15;
    int fg = lane >> 4;
    int wm0 = (wid / WN) * (BM / WM);
    int wn0 = (wid % WN) * (BN / WN);
    int mBase = blockIdx.x * BM;
    int nBase = blockIdx.y * BN;

    f32x4 acc[MI][NI];
#pragma unroll
    for (int mi = 0; mi < MI; ++mi)
#pragma unroll
        for (int ni = 0; ni < NI; ++ni) acc[mi][ni] = (f32x4)0.0f;

    constexpr int ACH = BM * BK / 8;
    constexpr int BCH = BN * BK / 8;

    const int KI = K / BK;
    for (int t = 0; t < KI; ++t) {
        int k0 = t * BK;
        for (int q = tid; q < ACH; q += THREADS) {
            int row = q >> 2;
            int sl = (q & 3) * 8;
            int gm = mBase + row;
            if (gm >= M) gm = M - 1;
            size_t off = (size_t)gm * K + k0 + sl;
            *(bf16x8*)&As[0][row][sl] = *(const bf16x8*)(Ah + off);
            *(bf16x8*)&As[1][row][sl] = *(const bf16x8*)(Al + off);
        }
        for (int q = tid; q < BCH; q += THREADS) {
            int row = q >> 2;
            int sl = (q & 3) * 8;
            size_t off = (size_t)(nBase + row) * K + k0 + sl;
            *(bf16x8*)&Bs[row][sl] = *(const bf16x8*)(Bh + off);
        }
        __syncthreads();

        bf16x8 afh[MI], afl[MI], bfh[NI];
#pragma unroll
        for (int mi = 0; mi < MI; ++mi) {
            afh[mi] = *(const bf16x8*)&As[0][wm0 + mi * 16 + fr][fg * 8];
            afl[mi] = *(const bf16x8*)&As[1][wm0 + mi * 16 + fr][fg * 8];
        }
#pragma unroll
        for (int ni = 0; ni < NI; ++ni)
            bfh[ni] = *(const bf16x8*)&Bs[wn0 + ni * 16 + fr][fg * 8];
#pragma unroll
        for (int mi = 0; mi < MI; ++mi)
#pragma unroll
            for (int ni = 0; ni < NI; ++ni) {
                acc[mi][ni] = __builtin_amdgcn_mfma_f32_16x16x32_bf16(
                    afh[mi], bfh[ni], acc[mi][ni], 0, 0, 0);
                acc[mi][ni] = __builtin_amdgcn_mfma_f32_16x16x32_bf16(
                    afl[mi], bfh[ni], acc[mi][ni], 0, 0, 0);
            }
        __syncthreads();
    }

    // ---- C write (bf16) ----
#pragma unroll
    for (int mi = 0; mi < MI; ++mi) {
#pragma unroll
        for (int j = 0; j < 4; ++j) {
            int gm = mBase + wm0 + mi * 16 + fg * 4 + j;
            if (gm >= M) continue;
#pragma unroll
            for (int ni = 0; ni < NI; ++ni) {
                int gn = nBase + wn0 + ni * 16 + fr;
                Cb[(size_t)gm * N + gn] = f2bf(acc[mi][ni][j]);
            }
        }
    }

    // ---- fused attention coefficients ----
    float asv[NI], adv[NI];
#pragma unroll
    for (int ni = 0; ni < NI; ++ni) {
        int col = wn0 + ni * 16 + fr;
        asv[ni] = a_src[col];
        adv[ni] = a_dst[col];
    }
    if constexpr (WN == H) {
        const int head = wn0 / (BN / H);
#pragma unroll
        for (int mi = 0; mi < MI; ++mi) {
#pragma unroll
            for (int j = 0; j < 4; ++j) {
                float ps = 0.0f, pd = 0.0f;
#pragma unroll
                for (int ni = 0; ni < NI; ++ni) {
                    ps += acc[mi][ni][j] * asv[ni];
                    pd += acc[mi][ni][j] * adv[ni];
                }
#pragma unroll
                for (int off = 1; off <= 8; off <<= 1) {
                    ps += __shfl_xor(ps, off);
                    pd += __shfl_xor(pd, off);
                }
                int gm = mBase + wm0 + mi * 16 + fg * 4 + j;
                if (fr == 0 && gm < M) {
                    e_s[(size_t)gm * H + head] = ps * LOG2E;
                    e_d[(size_t)gm * H + head] = pd * LOG2E;
                }
            }
        }
    } else {
        __shared__ float esb[WN][BM];
        __shared__ float edb[WN][BM];
        int wc = wid % WN;
#pragma unroll
        for (int mi = 0; mi < MI; ++mi) {
#pragma unroll
            for (int j = 0; j < 4; ++j) {
                float ps = 0.0f, pd = 0.0f;
#pragma unroll
                for (int ni = 0; ni < NI; ++ni) {
                    ps += acc[mi][ni][j] * asv[ni];
                    pd += acc[mi][ni][j] * adv[ni];
                }
#pragma unroll
                for (int off = 1; off <= 8; off <<= 1) {
                    ps += __shfl_xor(ps, off);
                    pd += __shfl_xor(pd, off);
                }
                if (fr == 0) {
                    int lr = wm0 + mi * 16 + fg * 4 + j;
                    esb[wc][lr] = ps;
                    edb[wc][lr] = pd;
                }
            }
        }
        __syncthreads();
        if (tid < BM) {
            int gm = mBase + tid;
            if (gm < M) {
                float ps = 0.0f, pd = 0.0f;
#pragma unroll
                for (int wcc = 0; wcc < WN; ++wcc) {
                    ps += esb[wcc][tid];
                    pd += edb[wcc][tid];
                }
                e_s[gm] = ps * LOG2E;
                e_d[gm] = pd * LOG2E;
            }
        }
        if (blockIdx.x == 0 && tid < 16) {
            ushort4 z = {0, 0, 0, 0};
            *(ushort4*)(Cb + (size_t)M * N + tid * 4) = z;
        }
    }
}

// ---------------- aggregation: padded one-pass softmax, bf16 gather --------
// Segments multiples of 8 with sentinel pads (p==0 exactly); exp2 domain;
// leaky(t) == fmax(t, 0.2t). Simple 32-VGPR loop (r10: pipelining halved
// occupancy and regressed). CLS=true fuses the classification head.

template<int HC, int H, bool ELU, bool SPLIT, bool CLS>
__global__ void aggregate(const ushort* __restrict__ hb,
                          const float* __restrict__ e_s, const float* __restrict__ e_d,
                          const int* __restrict__ offsets, const int* __restrict__ csr_src,
                          const float* __restrict__ bias,
                          float* __restrict__ out,
                          ushort* __restrict__ oh, ushort* __restrict__ ol,
                          const float* __restrict__ clsW, const float* __restrict__ clsB,
                          float* __restrict__ outN, int N) {
    int wid = (int)((blockIdx.x * (size_t)blockDim.x + threadIdx.x) >> 6);
    int lane = threadIdx.x & 63;
    if (wid >= N) return;
    constexpr int VEC = HC / 64;
    constexpr int C = HC / H;
    constexpr int ROWSH = (HC == 256) ? 9 : 7;      // log2(row bytes)
    int hd = (lane * VEC) / C;
    float ed = e_d[(size_t)wid * H + hd];
    int beg = offsets[wid], end = offsets[wid + 1];
    const char* hbB = (const char*)hb;
    const char* esB = (const char*)e_s;
    unsigned laneOff = (unsigned)lane * (VEC * 2);

    float s = 0.0f;
    float acc[VEC];
#pragma unroll
    for (int j = 0; j < VEC; ++j) acc[j] = 0.0f;

    for (int k = beg; k < end; k += 8) {
        int4 c0 = *(const int4*)(csr_src + k);       // segments 8-aligned
        int4 c1 = *(const int4*)(csr_src + k + 4);
        int sidx[8] = {c0.x, c0.y, c0.z, c0.w, c1.x, c1.y, c1.z, c1.w};
        float e[8];
#pragma unroll
        for (int u = 0; u < 8; ++u)
            e[u] = *(const float*)(esB + (((unsigned)(sidx[u] * H + hd)) << 2));
        ushort4 hv4[8];
        ushort  hv1[8];
        if constexpr (VEC == 4) {
#pragma unroll
            for (int u = 0; u < 8; ++u)
                hv4[u] = *(const ushort4*)(hbB + (((unsigned)sidx[u]) << ROWSH) + laneOff);
        } else {
#pragma unroll
            for (int u = 0; u < 8; ++u)
                hv1[u] = *(const ushort*)(hbB + (((unsigned)sidx[u]) << ROWSH) + laneOff);
        }
        float p[8];
        float psum = 0.0f;
#pragma unroll
        for (int u = 0; u < 8; ++u) {
            float t = e[u] + ed;
            t = fmaxf(t, 0.2f * t);                   // leaky relu (log2-domain)
            p[u] = __builtin_amdgcn_exp2f(t);
            psum += p[u];
        }
        s += psum;
        if constexpr (VEC == 4) {
#pragma unroll
            for (int u = 0; u < 8; ++u) {
                acc[0] += p[u] * bf2f(hv4[u].x);
                acc[1] += p[u] * bf2f(hv4[u].y);
                acc[2] += p[u] * bf2f(hv4[u].z);
                acc[3] += p[u] * bf2f(hv4[u].w);
            }
        } else {
#pragma unroll
            for (int u = 0; u < 8; ++u) acc[0] += p[u] * bf2f(hv1[u]);
        }
    }
    float inv = 1.0f / (s + 1e-16f);
    float o[VEC];
#pragma unroll
    for (int j = 0; j < VEC; ++j) {
        int f = lane * VEC + j;
        o[j] = acc[j] * inv + bias[f];
        if constexpr (ELU) o[j] = (o[j] > 0.0f) ? o[j] : expm1f(o[j]);
    }
    if constexpr (SPLIT) {
        if constexpr (VEC == 4) {
            ushort4 h4, l4;
            h4.x = f2bf(o[0]); l4.x = f2bf(o[0] - bf2f(h4.x));
            h4.y = f2bf(o[1]); l4.y = f2bf(o[1] - bf2f(h4.y));
            h4.z = f2bf(o[2]); l4.z = f2bf(o[2] - bf2f(h4.z));
            h4.w = f2bf(o[3]); l4.w = f2bf(o[3] - bf2f(h4.w));
            *(ushort4*)(oh + (size_t)wid * HC + lane * 4) = h4;
            *(ushort4*)(ol + (size_t)wid * HC + lane * 4) = l4;
        } else {
            ushort h1 = f2bf(o[0]);
            oh[(size_t)wid * HC + lane] = h1;
            ol[(size_t)wid * HC + lane] = f2bf(o[0] - bf2f(h1));
        }
    } else {
#pragma unroll
        for (int j = 0; j < VEC; ++j)
            out[(size_t)wid * HC + lane * VEC + j] = o[j];
    }
    if constexpr (CLS) {
        float p0 = o[0] * clsW[lane * 2 + 0];
        float p1 = o[0] * clsW[lane * 2 + 1];
#pragma unroll
        for (int off = 1; off <= 32; off <<= 1) {
            p0 += __shfl_xor(p0, off);
            p1 += __shfl_xor(p1, off);
        }
        if (lane == 0) {
            outN[(size_t)wid * 2 + 0] = p0 + clsB[0];
            outN[(size_t)wid * 2 + 1] = p1 + clsB[1];
        }
    }
}

// ---------------------------------------------------------------------------

extern "C" void kernel_launch(void* const* d_in, const int* in_sizes, int n_in,
                              void* d_out, int out_size, void* d_ws, size_t ws_size,
                              hipStream_t stream) {
    const float* x      = (const float*)d_in[0];
    const int*   ei     = (const int*)d_in[1];
    const float* W1     = (const float*)d_in[2];
    const float* a1_src = (const float*)d_in[3];
    const float* a1_dst = (const float*)d_in[4];
    const float* b1     = (const float*)d_in[5];
    const float* W2     = (const float*)d_in[6];
    const float* a2_src = (const float*)d_in[7];
    const float* a2_dst = (const float*)d_in[8];
    const float* b2     = (const float*)d_in[9];
    const float* W3     = (const float*)d_in[10];
    const float* a3_src = (const float*)d_in[11];
    const float* a3_dst = (const float*)d_in[12];
    const float* b3     = (const float*)d_in[13];
    const float* cls_W  = (const float*)d_in[14];
    const float* cls_b  = (const float*)d_in[15];

    const int N = in_sizes[0] / 128;     // 50000
    const int E = in_sizes[1] / 2;       // 800000
    const int ETcap = E + 8 * N + 64;    // padded CSR capacity bound
    const int HC = 256;
    const int nScanBlk = (N + 1023) / 1024;

    // ---- workspace carve-up (256B aligned) ----
    char* w = (char*)d_ws;
    auto carve = [&](size_t bytes) {
        char* p = w;
        w += (bytes + 255) & ~(size_t)255;
        return p;
    };
    int*    deg     = (int*)   carve((size_t)N * 4);
    int*    counter = (int*)   carve((size_t)N * 4);
    int*    offsets = (int*)   carve((size_t)(N + 1) * 4);
    int*    csr_src = (int*)   carve((size_t)ETcap * 4);
    int*    blkSums = (int*)   carve((size_t)64 * 4);
    int*    blkBase = (int*)   carve((size_t)64 * 4);
    float*  e_s     = (float*) carve((size_t)(N + 1) * 4 * 4);   // H=4 + sentinel
    float*  e_d     = (float*) carve((size_t)N * 4 * 4);
    float*  e_s3    = (float*) carve((size_t)(N + 1) * 4);       // H=1 + sentinel
    float*  e_d3    = (float*) carve((size_t)N * 4);
    ushort* hb      = (ushort*)carve((size_t)(N + 1) * HC * 2);  // + sentinel row
    ushort* Ahi     = (ushort*)carve((size_t)N * HC * 2);
    ushort* Alo     = (ushort*)carve((size_t)N * HC * 2);
    ushort* W1t     = (ushort*)carve((size_t)128 * 256 * 2);
    ushort* W2t     = (ushort*)carve((size_t)256 * 256 * 2);
    ushort* W3t     = (ushort*)carve((size_t)256 * 64 * 2);
    (void)ws_size;

    float* out_node = (float*)d_out;                  // [N,2]
    float* out_link = (float*)d_out + 2 * (size_t)N;  // [N,64]

    // ---- CSR build (padded to 8-edge batches, sentinel = N) ----
    hipMemsetAsync(deg, 0, (size_t)N * 4, stream);
    int eblocks = (E + 255) / 256;
    if (eblocks > 2048) eblocks = 2048;
    count_deg<<<eblocks, 256, 0, stream>>>(ei, E, deg);
    scan_local<<<nScanBlk, 256, 0, stream>>>(deg, offsets, blkSums, N);
    scan_blocks<<<1, 64, 0, stream>>>(blkSums, blkBase, offsets, N, nScanBlk);
    scan_add_fill<<<(N + 255) / 256, 256, 0, stream>>>(offsets, blkBase, deg,
                                                       counter, csr_src, N);
    fill_edges<<<eblocks, 256, 0, stream>>>(ei, E, offsets, counter, csr_src);

    // ---- fused prep: x split + weight transposes + sentinel rows ----
    const int X4 = N * 128 / 4;
    const int prepTotal = X4 + 32768 + 65536 + 16384 + 64 + 4 + 1;
    prep_all<<<(prepTotal + 255) / 256, 256, 0, stream>>>(
        x, Ahi, Alo, X4, W1, W2, W3, W1t, W2t, W3t, hb, e_s, e_s3, N);

    dim3 g12((N + 127) / 128, 1);   // BM=128, BN=256
    dim3 g3((N + 127) / 128, 1);    // BM=128, BN=64
    int nodeBlocks = (N + 3) / 4;

    // ---- layer 1: 128 -> 4x64 ----
    gemm_mfma<128, 256, 2, 4, 512, 4><<<g12, 512, 0, stream>>>(
        Ahi, Alo, W1t, hb, e_s, e_d, a1_src, a1_dst, N, 256, 128);
    aggregate<256, 4, true, true, false><<<nodeBlocks, 256, 0, stream>>>(
        hb, e_s, e_d, offsets, csr_src, b1, nullptr, Ahi, Alo,
        nullptr, nullptr, nullptr, N);
    // ---- layer 2: 256 -> 4x64 ----
    gemm_mfma<128, 256, 2, 4, 512, 4><<<g12, 512, 0, stream>>>(
        Ahi, Alo, W2t, hb, e_s, e_d, a2_src, a2_dst, N, 256, 256);
    aggregate<256, 4, true, true, false><<<nodeBlocks, 256, 0, stream>>>(
        hb, e_s, e_d, offsets, csr_src, b2, nullptr, Ahi, Alo,
        nullptr, nullptr, nullptr, N);
    // ---- layer 3: 256 -> 64 (1 head, mean==identity, fused cls head) ----
    gemm_mfma<128, 64, 4, 2, 512, 1><<<g3, 512, 0, stream>>>(
        Ahi, Alo, W3t, hb, e_s3, e_d3, a3_src, a3_dst, N, 64, 256);
    aggregate<64, 1, false, false, true><<<nodeBlocks, 256, 0, stream>>>(
        hb, e_s3, e_d3, offsets, csr_src, b3, out_link, nullptr, nullptr,
        cls_W, cls_b, out_node, N);
}